// Round 2
// baseline (531.142 us; speedup 1.0000x reference)
//
#include <hip/hip_runtime.h>
#include <hip/hip_bf16.h>
#include <cstdint>

typedef unsigned short U16;
typedef float f32x4 __attribute__((ext_vector_type(4)));
typedef __bf16 bf16x8 __attribute__((ext_vector_type(8)));

#define DEVINL __device__ __forceinline__

DEVINL U16 f2bf(float f) {
    unsigned u = __float_as_uint(f);
    return (U16)((u + 0x7FFFu + ((u >> 16) & 1u)) >> 16);  // RN-even
}
DEVINL float bf2f(U16 s) { return __uint_as_float(((unsigned)s) << 16); }

DEVINL void gld16(const void* g, void* l) {
    __builtin_amdgcn_global_load_lds(
        (const __attribute__((address_space(1))) void*)g,
        (__attribute__((address_space(3))) void*)l, 16, 0, 0);
}

// ---------------- weight transpose + cast: wt[n][k] = (bf16) w[k][n] ----------------
__global__ __launch_bounds__(256) void tcast_kernel(const float* __restrict__ w,
                                                    U16* __restrict__ wt, int K, int N) {
    __shared__ float tile[32][33];
    int n0 = blockIdx.x * 32, k0 = blockIdx.y * 32;
    int tx = threadIdx.x, ty = threadIdx.y;  // 32 x 8
#pragma unroll
    for (int i = 0; i < 32; i += 8) tile[ty + i][tx] = w[(size_t)(k0 + ty + i) * N + (n0 + tx)];
    __syncthreads();
#pragma unroll
    for (int i = 0; i < 32; i += 8) wt[(size_t)(n0 + ty + i) * K + (k0 + tx)] = f2bf(tile[tx][ty + i]);
}

// ---------------- LayerNorm over 512, one wave per row, bf16 out ----------------
__global__ __launch_bounds__(256) void ln_kernel(const float* __restrict__ x,
                                                 const float* __restrict__ g,
                                                 const float* __restrict__ b,
                                                 U16* __restrict__ out) {
    int lane = threadIdx.x & 63;
    size_t row = (size_t)blockIdx.x * 4 + (threadIdx.x >> 6);
    const float4* xr = (const float4*)(x + row * 512);
    float4 v0 = xr[lane], v1 = xr[lane + 64];
    float s = (v0.x + v0.y) + (v0.z + v0.w) + (v1.x + v1.y) + (v1.z + v1.w);
    float sq = (v0.x * v0.x + v0.y * v0.y + v0.z * v0.z + v0.w * v0.w) +
               (v1.x * v1.x + v1.y * v1.y + v1.z * v1.z + v1.w * v1.w);
#pragma unroll
    for (int m = 1; m < 64; m <<= 1) { s += __shfl_xor(s, m); sq += __shfl_xor(sq, m); }
    float mu = s * (1.f / 512.f);
    float var = sq * (1.f / 512.f) - mu * mu;
    float rs = rsqrtf(var + 1e-5f);
    const float4* g4 = (const float4*)g;
    const float4* b4 = (const float4*)b;
    float4 gv = g4[lane], bv = b4[lane];
    ushort4 o;
    o.x = f2bf((v0.x - mu) * rs * gv.x + bv.x);
    o.y = f2bf((v0.y - mu) * rs * gv.y + bv.y);
    o.z = f2bf((v0.z - mu) * rs * gv.z + bv.z);
    o.w = f2bf((v0.w - mu) * rs * gv.w + bv.w);
    ((ushort4*)(out + row * 512))[lane] = o;
    gv = g4[lane + 64]; bv = b4[lane + 64];
    o.x = f2bf((v1.x - mu) * rs * gv.x + bv.x);
    o.y = f2bf((v1.y - mu) * rs * gv.y + bv.y);
    o.z = f2bf((v1.z - mu) * rs * gv.z + bv.z);
    o.w = f2bf((v1.w - mu) * rs * gv.w + bv.w);
    ((ushort4*)(out + row * 512))[lane + 64] = o;
}

// ---------------- GEMM: C[M,N] = A[M,K](bf16) * Bt[N,K](bf16)^T + bias, epilogues ----------------
// EPI 0: bf16 out (bias)         -> outb   (LDS-staged coalesced stores)
// EPI 1: fp32 out (bias + resid) -> outf   (direct, j-inner full-line stores)
// EPI 2: bf16 out (bias + gelu)  -> outb   (LDS-staged coalesced stores)
// Tile 128x128, BK=64, 4 waves (2x2), XOR-chunk-swizzled LDS, XCD-chunked grid swizzle.
template <int EPI>
__global__ __launch_bounds__(256) void gemm_bt(const U16* __restrict__ A,
                                               const U16* __restrict__ Bt,
                                               const float* __restrict__ bias,
                                               const float* __restrict__ resid,
                                               U16* __restrict__ outb,
                                               float* __restrict__ outf,
                                               int M, int N, int K, int gridN) {
    __shared__ __align__(16) U16 smem[2 * 128 * 64];
    U16* As = smem;
    U16* Bs = smem + 128 * 64;

    const int tid = threadIdx.x;
    const int lane = tid & 63, wv = tid >> 6;
    const int lo = lane & 15, hi = lane >> 4;
    const int wm = wv >> 1, wn = wv & 1;  // 2x2 wave grid, 64x64 per wave

    // XCD-chunked bijective swizzle (nwg % 8 == 0 for all our launches)
    const int nwg = gridDim.x;
    const int bid = blockIdx.x;
    const int swz = (bid & 7) * (nwg >> 3) + (bid >> 3);
    const int bn = swz % gridN, bm = swz / gridN;

    // staging: thread handles physical chunk (tid&7) of row (q*32 + (tid>>3)), q=0..3
    // physical chunk p holds logical chunk p ^ (row&7) -> pre-swizzle global source
    const int sr = tid >> 3;
    const int lc = (tid & 7) ^ (sr & 7);
    const U16* gA = A + (size_t)(bm * 128 + sr) * K + lc * 8;
    const U16* gB = Bt + (size_t)(bn * 128 + sr) * K + lc * 8;
    U16* lA = As + tid * 8;
    U16* lB = Bs + tid * 8;

    f32x4 acc[4][4] = {};

    for (int k0 = 0; k0 < K; k0 += 64) {
#pragma unroll
        for (int q = 0; q < 4; q++) gld16(gA + (size_t)q * 32 * K, lA + q * 2048);
#pragma unroll
        for (int q = 0; q < 4; q++) gld16(gB + (size_t)q * 32 * K, lB + q * 2048);
        gA += 64; gB += 64;
        __syncthreads();
#pragma unroll
        for (int kk = 0; kk < 2; kk++) {
            bf16x8 af[4], bfr[4];
#pragma unroll
            for (int i = 0; i < 4; i++) {
                const int row = wm * 64 + i * 16 + lo;
                af[i] = *(const bf16x8*)&As[row * 64 + (((kk << 2) | hi) ^ (lo & 7)) * 8];
            }
#pragma unroll
            for (int j = 0; j < 4; j++) {
                const int row = wn * 64 + j * 16 + lo;
                bfr[j] = *(const bf16x8*)&Bs[row * 64 + (((kk << 2) | hi) ^ (lo & 7)) * 8];
            }
#pragma unroll
            for (int i = 0; i < 4; i++)
#pragma unroll
                for (int j = 0; j < 4; j++)
                    acc[i][j] = __builtin_amdgcn_mfma_f32_16x16x32_bf16(af[i], bfr[j], acc[i][j], 0, 0, 0);
        }
        __syncthreads();
    }

    // bias for this thread's 4 column groups
    const int col0 = bn * 128 + wn * 64 + lo;
    float bc[4];
#pragma unroll
    for (int j = 0; j < 4; j++) bc[j] = bias[col0 + j * 16];

    if (EPI == 1) {
        // fp32 out = acc + bias + resid ; i,r outer, j inner for full-line merging
        const int row0 = bm * 128 + wm * 64 + hi * 4;
#pragma unroll
        for (int i = 0; i < 4; i++)
#pragma unroll
            for (int r = 0; r < 4; r++) {
                const size_t rowb = (size_t)(row0 + i * 16 + r) * N;
#pragma unroll
                for (int j = 0; j < 4; j++) {
                    const size_t idx = rowb + col0 + j * 16;
                    outf[idx] = acc[i][j][r] + bc[j] + resid[idx];
                }
            }
    } else {
        // bf16 out via LDS staging, 2 passes of 64 rows (stride 136 U16)
        const int CST = 136;
        const int crow = tid >> 2;        // 0..63
        const int cci = tid & 3;
#pragma unroll
        for (int p = 0; p < 2; p++) {
            if (p) __syncthreads();
            if (wm == p) {
#pragma unroll
                for (int i = 0; i < 4; i++)
#pragma unroll
                    for (int j = 0; j < 4; j++)
#pragma unroll
                        for (int r = 0; r < 4; r++) {
                            float v = acc[i][j][r] + bc[j];
                            if (EPI == 2) v = 0.5f * v * (1.f + erff(v * 0.70710678118654752f));
                            smem[(i * 16 + hi * 4 + r) * CST + wn * 64 + j * 16 + lo] = f2bf(v);
                        }
            }
            __syncthreads();
            U16* gout = outb + (size_t)(bm * 128 + p * 64 + crow) * N + bn * 128;
#pragma unroll
            for (int k = 0; k < 4; k++) {
                const int c = (cci + k * 4) * 8;
                *(bf16x8*)(gout + c) = *(const bf16x8*)&smem[crow * CST + c];
            }
        }
    }
}

// ---------------- windowed attention: one block per (window, head) ----------------
// qkv: [32768][1536] bf16, layout [3][8][64] in last dim. o: [32768][512] bf16.
__global__ __launch_bounds__(256) void attn_kernel(const U16* __restrict__ qkv,
                                                   U16* __restrict__ o) {
    const int blk = blockIdx.x;
    const int w = blk >> 3, h = blk & 7;
    const int tid = threadIdx.x;
    const int lane = tid & 63, wv = tid >> 6;
    const int lo = lane & 15, hi = lane >> 4;

    __shared__ __align__(16) U16 Qs[64][72];
    __shared__ __align__(16) U16 Ks[64][72];
    __shared__ __align__(16) U16 Vt[64][72];  // V transposed: Vt[d][j]
    __shared__ __align__(16) U16 Ps[4][16][72];

    {
        const int r = tid >> 2;
        const int c0 = (tid & 3) << 4;
        const U16* p = qkv + (size_t)(w * 64 + r) * 1536 + h * 64 + c0;
        *(bf16x8*)&Ks[r][c0] = *(const bf16x8*)(p + 512);
        *(bf16x8*)&Ks[r][c0 + 8] = *(const bf16x8*)(p + 520);
        const U16* pv = p + 1024;
#pragma unroll
        for (int i = 0; i < 16; i++) Vt[c0 + i][r] = pv[i];
#pragma unroll
        for (int i = 0; i < 16; i++) Qs[r][c0 + i] = f2bf(bf2f(p[i]) * 0.125f);
    }
    __syncthreads();

    const int rb = wv * 16;  // this wave's 16 score rows
    f32x4 s[4] = {};
#pragma unroll
    for (int dc = 0; dc < 64; dc += 32) {
        bf16x8 a = *(const bf16x8*)&Qs[rb + lo][dc + hi * 8];
#pragma unroll
        for (int jb = 0; jb < 4; jb++) {
            bf16x8 bfr = *(const bf16x8*)&Ks[jb * 16 + lo][dc + hi * 8];
            s[jb] = __builtin_amdgcn_mfma_f32_16x16x32_bf16(a, bfr, s[jb], 0, 0, 0);
        }
    }
#pragma unroll
    for (int r = 0; r < 4; r++) {
        float m = fmaxf(fmaxf(s[0][r], s[1][r]), fmaxf(s[2][r], s[3][r]));
#pragma unroll
        for (int msk = 1; msk < 16; msk <<= 1) m = fmaxf(m, __shfl_xor(m, msk));
        float e[4], sum = 0.f;
#pragma unroll
        for (int jb = 0; jb < 4; jb++) { e[jb] = expf(s[jb][r] - m); sum += e[jb]; }
#pragma unroll
        for (int msk = 1; msk < 16; msk <<= 1) sum += __shfl_xor(sum, msk);
        float inv = 1.f / sum;
#pragma unroll
        for (int jb = 0; jb < 4; jb++) Ps[wv][hi * 4 + r][jb * 16 + lo] = f2bf(e[jb] * inv);
    }
    __syncthreads();

    f32x4 oa[4] = {};
#pragma unroll
    for (int jc = 0; jc < 64; jc += 32) {
        bf16x8 a = *(const bf16x8*)&Ps[wv][lo][jc + hi * 8];
#pragma unroll
        for (int db = 0; db < 4; db++) {
            bf16x8 bfr = *(const bf16x8*)&Vt[db * 16 + lo][jc + hi * 8];
            oa[db] = __builtin_amdgcn_mfma_f32_16x16x32_bf16(a, bfr, oa[db], 0, 0, 0);
        }
    }
#pragma unroll
    for (int db = 0; db < 4; db++)
#pragma unroll
        for (int r = 0; r < 4; r++)
            o[(size_t)(w * 64 + rb + hi * 4 + r) * 512 + h * 64 + db * 16 + lo] = f2bf(oa[db][r]);
}

// ---------------- launch ----------------
extern "C" void kernel_launch(void* const* d_in, const int* in_sizes, int n_in,
                              void* d_out, int out_size, void* d_ws, size_t ws_size,
                              hipStream_t stream) {
    const float* x = (const float*)d_in[0];
    const float* ln1_g = (const float*)d_in[1];
    const float* ln1_b = (const float*)d_in[2];
    const float* qkv_w = (const float*)d_in[3];
    const float* qkv_b = (const float*)d_in[4];
    const float* proj_w = (const float*)d_in[5];
    const float* proj_b = (const float*)d_in[6];
    const float* ln2_g = (const float*)d_in[7];
    const float* ln2_b = (const float*)d_in[8];
    const float* fc1_w = (const float*)d_in[9];
    const float* fc1_b = (const float*)d_in[10];
    const float* fc2_w = (const float*)d_in[11];
    const float* fc2_b = (const float*)d_in[12];
    float* out = (float*)d_out;

    char* ws = (char*)d_ws;
    U16* hbuf = (U16*)ws;                               // 32768*512 bf16
    U16* big = (U16*)(ws + 33554432);                   // 32768*2048 bf16 max
    U16* wt_qkv = (U16*)(ws + 33554432 + 134217728);    // 1536*512
    U16* wt_proj = wt_qkv + 1536 * 512;                 // 512*512
    U16* wt_fc1 = wt_proj + 512 * 512;                  // 2048*512
    U16* wt_fc2 = wt_fc1 + 2048 * 512;                  // 512*2048

    dim3 tb(32, 8);
    tcast_kernel<<<dim3(1536 / 32, 512 / 32), tb, 0, stream>>>(qkv_w, wt_qkv, 512, 1536);
    tcast_kernel<<<dim3(512 / 32, 512 / 32), tb, 0, stream>>>(proj_w, wt_proj, 512, 512);
    tcast_kernel<<<dim3(2048 / 32, 512 / 32), tb, 0, stream>>>(fc1_w, wt_fc1, 512, 2048);
    tcast_kernel<<<dim3(512 / 32, 2048 / 32), tb, 0, stream>>>(fc2_w, wt_fc2, 2048, 512);

    ln_kernel<<<8192, 256, 0, stream>>>(x, ln1_g, ln1_b, hbuf);
    gemm_bt<0><<<12 * 256, 256, 0, stream>>>(hbuf, wt_qkv, qkv_b, nullptr, big, nullptr, 32768, 1536, 512, 12);
    attn_kernel<<<4096, 256, 0, stream>>>(big, hbuf);
    gemm_bt<1><<<4 * 256, 256, 0, stream>>>(hbuf, wt_proj, proj_b, x, nullptr, out, 32768, 512, 512, 4);
    ln_kernel<<<8192, 256, 0, stream>>>(out, ln2_g, ln2_b, hbuf);
    gemm_bt<2><<<16 * 256, 256, 0, stream>>>(hbuf, wt_fc1, fc1_b, nullptr, big, nullptr, 32768, 2048, 512, 16);
    gemm_bt<1><<<4 * 256, 256, 0, stream>>>(big, wt_fc2, fc2_b, out, nullptr, out, 32768, 512, 2048, 4);
}

// Round 3
// 516.701 us; speedup vs baseline: 1.0279x; 1.0279x over previous
//
#include <hip/hip_runtime.h>
#include <hip/hip_bf16.h>
#include <cstdint>

typedef unsigned short U16;
typedef float f32x4 __attribute__((ext_vector_type(4)));
typedef __bf16 bf16x8 __attribute__((ext_vector_type(8)));

#define DEVINL __device__ __forceinline__

DEVINL U16 f2bf(float f) {
    unsigned u = __float_as_uint(f);
    return (U16)((u + 0x7FFFu + ((u >> 16) & 1u)) >> 16);  // RN-even
}
DEVINL float bf2f(U16 s) { return __uint_as_float(((unsigned)s) << 16); }

DEVINL void gld16(const void* g, void* l) {
    __builtin_amdgcn_global_load_lds(
        (const __attribute__((address_space(1))) void*)g,
        (__attribute__((address_space(3))) void*)l, 16, 0, 0);
}

// ---------------- weight transpose + cast: wt[n][k] = (bf16) w[k][n] ----------------
__global__ __launch_bounds__(256) void tcast_kernel(const float* __restrict__ w,
                                                    U16* __restrict__ wt, int K, int N) {
    __shared__ float tile[32][33];
    int n0 = blockIdx.x * 32, k0 = blockIdx.y * 32;
    int tx = threadIdx.x, ty = threadIdx.y;  // 32 x 8
#pragma unroll
    for (int i = 0; i < 32; i += 8) tile[ty + i][tx] = w[(size_t)(k0 + ty + i) * N + (n0 + tx)];
    __syncthreads();
#pragma unroll
    for (int i = 0; i < 32; i += 8) wt[(size_t)(n0 + ty + i) * K + (k0 + tx)] = f2bf(tile[tx][ty + i]);
}

// ---------------- LayerNorm over 512, one wave per row, bf16 out ----------------
__global__ __launch_bounds__(256) void ln_kernel(const float* __restrict__ x,
                                                 const float* __restrict__ g,
                                                 const float* __restrict__ b,
                                                 U16* __restrict__ out) {
    int lane = threadIdx.x & 63;
    size_t row = (size_t)blockIdx.x * 4 + (threadIdx.x >> 6);
    const float4* xr = (const float4*)(x + row * 512);
    float4 v0 = xr[lane], v1 = xr[lane + 64];
    float s = (v0.x + v0.y) + (v0.z + v0.w) + (v1.x + v1.y) + (v1.z + v1.w);
    float sq = (v0.x * v0.x + v0.y * v0.y + v0.z * v0.z + v0.w * v0.w) +
               (v1.x * v1.x + v1.y * v1.y + v1.z * v1.z + v1.w * v1.w);
#pragma unroll
    for (int m = 1; m < 64; m <<= 1) { s += __shfl_xor(s, m); sq += __shfl_xor(sq, m); }
    float mu = s * (1.f / 512.f);
    float var = sq * (1.f / 512.f) - mu * mu;
    float rs = rsqrtf(var + 1e-5f);
    const float4* g4 = (const float4*)g;
    const float4* b4 = (const float4*)b;
    float4 gv = g4[lane], bv = b4[lane];
    ushort4 o;
    o.x = f2bf((v0.x - mu) * rs * gv.x + bv.x);
    o.y = f2bf((v0.y - mu) * rs * gv.y + bv.y);
    o.z = f2bf((v0.z - mu) * rs * gv.z + bv.z);
    o.w = f2bf((v0.w - mu) * rs * gv.w + bv.w);
    ((ushort4*)(out + row * 512))[lane] = o;
    gv = g4[lane + 64]; bv = b4[lane + 64];
    o.x = f2bf((v1.x - mu) * rs * gv.x + bv.x);
    o.y = f2bf((v1.y - mu) * rs * gv.y + bv.y);
    o.z = f2bf((v1.z - mu) * rs * gv.z + bv.z);
    o.w = f2bf((v1.w - mu) * rs * gv.w + bv.w);
    ((ushort4*)(out + row * 512))[lane + 64] = o;
}

// ---------------- GEMM: C[M,N] = A[M,K](bf16) * Bt[N,K](bf16)^T + bias, epilogues ----------------
// EPI 0: bf16 out (bias)         -> outb   (LDS-staged coalesced stores)
// EPI 1: fp32 out (bias + resid) -> outf   (direct, j-inner full-line stores)
// EPI 2: bf16 out (bias + gelu)  -> outb   (LDS-staged coalesced stores)
// Round-1 main loop: tile 128x128, BK=32, 4 waves (2x2), LINEAR LDS (m97 structure).
// Plus: XCD-chunked bijective grid swizzle, coalesced epilogues.
template <int EPI>
__global__ __launch_bounds__(256) void gemm_bt(const U16* __restrict__ A,
                                               const U16* __restrict__ Bt,
                                               const float* __restrict__ bias,
                                               const float* __restrict__ resid,
                                               U16* __restrict__ outb,
                                               float* __restrict__ outf,
                                               int M, int N, int K, int gridN) {
    // 8704 U16: loop uses [0,4096) = As, [4096,8192) = Bs; epilogue reuses as 64x136 stage
    __shared__ __align__(16) U16 smem[8704];
    U16* As = smem;
    U16* Bs = smem + 4096;

    const int tid = threadIdx.x;
    const int lane = tid & 63, wv = tid >> 6;
    const int lo = lane & 15, hi = lane >> 4;
    const int wm = wv >> 1, wn = wv & 1;  // 2x2 wave grid, 64x64 per wave

    // XCD-chunked bijective swizzle (nwg % 8 == 0 for all our launches)
    const int nwg = gridDim.x;
    const int bid = blockIdx.x;
    const int swz = (bid & 7) * (nwg >> 3) + (bid >> 3);
    const int bn = swz % gridN, bm = swz / gridN;

    // staging (round-1): per wave rows [wv*32, wv*32+32); LDS dst = uniform base + lane*16B
    const int srow = wv * 32 + (lane >> 2);
    const int sk = (lane & 3) * 8;

    const U16* ga = A + (size_t)(bm * 128 + srow) * K + sk;
    const U16* gb = Bt + (size_t)(bn * 128 + srow) * K + sk;
    U16* la = &As[srow * 32 + sk];
    U16* lb = &Bs[srow * 32 + sk];

    f32x4 acc[4][4] = {};

    for (int k0 = 0; k0 < K; k0 += 32) {
        gld16(ga, la);
        gld16(ga + (size_t)16 * K, la + 16 * 32);
        gld16(gb, lb);
        gld16(gb + (size_t)16 * K, lb + 16 * 32);
        ga += 32; gb += 32;
        __syncthreads();
        bf16x8 af[4], bfr[4];
#pragma unroll
        for (int i = 0; i < 4; i++) af[i] = *(const bf16x8*)&As[(wm * 64 + i * 16 + lo) * 32 + hi * 8];
#pragma unroll
        for (int j = 0; j < 4; j++) bfr[j] = *(const bf16x8*)&Bs[(wn * 64 + j * 16 + lo) * 32 + hi * 8];
#pragma unroll
        for (int i = 0; i < 4; i++)
#pragma unroll
            for (int j = 0; j < 4; j++)
                acc[i][j] = __builtin_amdgcn_mfma_f32_16x16x32_bf16(af[i], bfr[j], acc[i][j], 0, 0, 0);
        __syncthreads();
    }

    // bias for this thread's 4 column groups
    const int col0 = bn * 128 + wn * 64 + lo;
    float bc[4];
#pragma unroll
    for (int j = 0; j < 4; j++) bc[j] = bias[col0 + j * 16];

    if (EPI == 1) {
        // fp32 out = acc + bias + resid ; i,r outer, j inner for full-line merging
        const int row0 = bm * 128 + wm * 64 + hi * 4;
#pragma unroll
        for (int i = 0; i < 4; i++)
#pragma unroll
            for (int r = 0; r < 4; r++) {
                const size_t rowb = (size_t)(row0 + i * 16 + r) * N;
#pragma unroll
                for (int j = 0; j < 4; j++) {
                    const size_t idx = rowb + col0 + j * 16;
                    outf[idx] = acc[i][j][r] + bc[j] + resid[idx];
                }
            }
    } else {
        // bf16 out via LDS staging, 2 passes of 64 rows (stride 136 U16)
        const int CST = 136;
        const int crow = tid >> 2;        // 0..63
        const int cci = tid & 3;
#pragma unroll
        for (int p = 0; p < 2; p++) {
            __syncthreads();
            if (wm == p) {
#pragma unroll
                for (int i = 0; i < 4; i++)
#pragma unroll
                    for (int j = 0; j < 4; j++)
#pragma unroll
                        for (int r = 0; r < 4; r++) {
                            float v = acc[i][j][r] + bc[j];
                            if (EPI == 2) v = 0.5f * v * (1.f + erff(v * 0.70710678118654752f));
                            smem[(i * 16 + hi * 4 + r) * CST + wn * 64 + j * 16 + lo] = f2bf(v);
                        }
            }
            __syncthreads();
            U16* gout = outb + (size_t)(bm * 128 + p * 64 + crow) * N + bn * 128;
#pragma unroll
            for (int k = 0; k < 4; k++) {
                const int c = (cci + k * 4) * 8;
                *(bf16x8*)(gout + c) = *(const bf16x8*)&smem[crow * CST + c];
            }
        }
    }
}

// ---------------- windowed attention: one block per (window, head) ----------------
// qkv: [32768][1536] bf16, layout [3][8][64] in last dim. o: [32768][512] bf16.
__global__ __launch_bounds__(256) void attn_kernel(const U16* __restrict__ qkv,
                                                   U16* __restrict__ o) {
    const int blk = blockIdx.x;
    const int w = blk >> 3, h = blk & 7;
    const int tid = threadIdx.x;
    const int lane = tid & 63, wv = tid >> 6;
    const int lo = lane & 15, hi = lane >> 4;

    __shared__ __align__(16) U16 Qs[64][72];
    __shared__ __align__(16) U16 Ks[64][72];
    __shared__ __align__(16) U16 Vt[64][72];  // V transposed: Vt[d][j]
    __shared__ __align__(16) U16 Ps[4][16][72];

    {
        const int r = tid >> 2;
        const int c0 = (tid & 3) << 4;
        const U16* p = qkv + (size_t)(w * 64 + r) * 1536 + h * 64 + c0;
        *(bf16x8*)&Ks[r][c0] = *(const bf16x8*)(p + 512);
        *(bf16x8*)&Ks[r][c0 + 8] = *(const bf16x8*)(p + 520);
        const U16* pv = p + 1024;
#pragma unroll
        for (int i = 0; i < 16; i++) Vt[c0 + i][r] = pv[i];
#pragma unroll
        for (int i = 0; i < 16; i++) Qs[r][c0 + i] = f2bf(bf2f(p[i]) * 0.125f);
    }
    __syncthreads();

    const int rb = wv * 16;  // this wave's 16 score rows
    f32x4 s[4] = {};
#pragma unroll
    for (int dc = 0; dc < 64; dc += 32) {
        bf16x8 a = *(const bf16x8*)&Qs[rb + lo][dc + hi * 8];
#pragma unroll
        for (int jb = 0; jb < 4; jb++) {
            bf16x8 bfr = *(const bf16x8*)&Ks[jb * 16 + lo][dc + hi * 8];
            s[jb] = __builtin_amdgcn_mfma_f32_16x16x32_bf16(a, bfr, s[jb], 0, 0, 0);
        }
    }
#pragma unroll
    for (int r = 0; r < 4; r++) {
        float m = fmaxf(fmaxf(s[0][r], s[1][r]), fmaxf(s[2][r], s[3][r]));
#pragma unroll
        for (int msk = 1; msk < 16; msk <<= 1) m = fmaxf(m, __shfl_xor(m, msk));
        float e[4], sum = 0.f;
#pragma unroll
        for (int jb = 0; jb < 4; jb++) { e[jb] = expf(s[jb][r] - m); sum += e[jb]; }
#pragma unroll
        for (int msk = 1; msk < 16; msk <<= 1) sum += __shfl_xor(sum, msk);
        float inv = 1.f / sum;
#pragma unroll
        for (int jb = 0; jb < 4; jb++) Ps[wv][hi * 4 + r][jb * 16 + lo] = f2bf(e[jb] * inv);
    }
    __syncthreads();

    f32x4 oa[4] = {};
#pragma unroll
    for (int jc = 0; jc < 64; jc += 32) {
        bf16x8 a = *(const bf16x8*)&Ps[wv][lo][jc + hi * 8];
#pragma unroll
        for (int db = 0; db < 4; db++) {
            bf16x8 bfr = *(const bf16x8*)&Vt[db * 16 + lo][jc + hi * 8];
            oa[db] = __builtin_amdgcn_mfma_f32_16x16x32_bf16(a, bfr, oa[db], 0, 0, 0);
        }
    }
#pragma unroll
    for (int db = 0; db < 4; db++)
#pragma unroll
        for (int r = 0; r < 4; r++)
            o[(size_t)(w * 64 + rb + hi * 4 + r) * 512 + h * 64 + db * 16 + lo] = f2bf(oa[db][r]);
}

// ---------------- launch ----------------
extern "C" void kernel_launch(void* const* d_in, const int* in_sizes, int n_in,
                              void* d_out, int out_size, void* d_ws, size_t ws_size,
                              hipStream_t stream) {
    const float* x = (const float*)d_in[0];
    const float* ln1_g = (const float*)d_in[1];
    const float* ln1_b = (const float*)d_in[2];
    const float* qkv_w = (const float*)d_in[3];
    const float* qkv_b = (const float*)d_in[4];
    const float* proj_w = (const float*)d_in[5];
    const float* proj_b = (const float*)d_in[6];
    const float* ln2_g = (const float*)d_in[7];
    const float* ln2_b = (const float*)d_in[8];
    const float* fc1_w = (const float*)d_in[9];
    const float* fc1_b = (const float*)d_in[10];
    const float* fc2_w = (const float*)d_in[11];
    const float* fc2_b = (const float*)d_in[12];
    float* out = (float*)d_out;

    char* ws = (char*)d_ws;
    U16* hbuf = (U16*)ws;                               // 32768*512 bf16
    U16* big = (U16*)(ws + 33554432);                   // 32768*2048 bf16 max
    U16* wt_qkv = (U16*)(ws + 33554432 + 134217728);    // 1536*512
    U16* wt_proj = wt_qkv + 1536 * 512;                 // 512*512
    U16* wt_fc1 = wt_proj + 512 * 512;                  // 2048*512
    U16* wt_fc2 = wt_fc1 + 2048 * 512;                  // 512*2048

    dim3 tb(32, 8);
    tcast_kernel<<<dim3(1536 / 32, 512 / 32), tb, 0, stream>>>(qkv_w, wt_qkv, 512, 1536);
    tcast_kernel<<<dim3(512 / 32, 512 / 32), tb, 0, stream>>>(proj_w, wt_proj, 512, 512);
    tcast_kernel<<<dim3(2048 / 32, 512 / 32), tb, 0, stream>>>(fc1_w, wt_fc1, 512, 2048);
    tcast_kernel<<<dim3(512 / 32, 2048 / 32), tb, 0, stream>>>(fc2_w, wt_fc2, 2048, 512);

    ln_kernel<<<8192, 256, 0, stream>>>(x, ln1_g, ln1_b, hbuf);
    gemm_bt<0><<<12 * 256, 256, 0, stream>>>(hbuf, wt_qkv, qkv_b, nullptr, big, nullptr, 32768, 1536, 512, 12);
    attn_kernel<<<4096, 256, 0, stream>>>(big, hbuf);
    gemm_bt<1><<<4 * 256, 256, 0, stream>>>(hbuf, wt_proj, proj_b, x, nullptr, out, 32768, 512, 512, 4);
    ln_kernel<<<8192, 256, 0, stream>>>(out, ln2_g, ln2_b, hbuf);
    gemm_bt<2><<<16 * 256, 256, 0, stream>>>(hbuf, wt_fc1, fc1_b, nullptr, big, nullptr, 32768, 2048, 512, 16);
    gemm_bt<1><<<4 * 256, 256, 0, stream>>>(big, wt_fc2, fc2_b, out, nullptr, out, 32768, 512, 2048, 4);
}

// Round 4
// 400.457 us; speedup vs baseline: 1.3263x; 1.2903x over previous
//
#include <hip/hip_runtime.h>
#include <hip/hip_bf16.h>
#include <cstdint>

typedef unsigned short U16;
typedef float f32x4 __attribute__((ext_vector_type(4)));
typedef __bf16 bf16x8 __attribute__((ext_vector_type(8)));

#define DEVINL __device__ __forceinline__

DEVINL U16 f2bf(float f) {
    unsigned u = __float_as_uint(f);
    return (U16)((u + 0x7FFFu + ((u >> 16) & 1u)) >> 16);  // RN-even
}
DEVINL float bf2f(U16 s) { return __uint_as_float(((unsigned)s) << 16); }

DEVINL void gld16(const void* g, void* l) {
    __builtin_amdgcn_global_load_lds(
        (const __attribute__((address_space(1))) void*)g,
        (__attribute__((address_space(3))) void*)l, 16, 0, 0);
}

#define MFMA_BF16 __builtin_amdgcn_mfma_f32_16x16x32_bf16

// ---------------- weight transpose + cast: wt[n][k] = (bf16) w[k][n] ----------------
__global__ __launch_bounds__(256) void tcast_kernel(const float* __restrict__ w,
                                                    U16* __restrict__ wt, int K, int N) {
    __shared__ float tile[32][33];
    int n0 = blockIdx.x * 32, k0 = blockIdx.y * 32;
    int tx = threadIdx.x, ty = threadIdx.y;  // 32 x 8
#pragma unroll
    for (int i = 0; i < 32; i += 8) tile[ty + i][tx] = w[(size_t)(k0 + ty + i) * N + (n0 + tx)];
    __syncthreads();
#pragma unroll
    for (int i = 0; i < 32; i += 8) wt[(size_t)(n0 + ty + i) * K + (k0 + tx)] = f2bf(tile[tx][ty + i]);
}

// ---------------- LayerNorm over 512, one wave per row, bf16 out ----------------
__global__ __launch_bounds__(256) void ln_kernel(const float* __restrict__ x,
                                                 const float* __restrict__ g,
                                                 const float* __restrict__ b,
                                                 U16* __restrict__ out) {
    int lane = threadIdx.x & 63;
    size_t row = (size_t)blockIdx.x * 4 + (threadIdx.x >> 6);
    const float4* xr = (const float4*)(x + row * 512);
    float4 v0 = xr[lane], v1 = xr[lane + 64];
    float s = (v0.x + v0.y) + (v0.z + v0.w) + (v1.x + v1.y) + (v1.z + v1.w);
    float sq = (v0.x * v0.x + v0.y * v0.y + v0.z * v0.z + v0.w * v0.w) +
               (v1.x * v1.x + v1.y * v1.y + v1.z * v1.z + v1.w * v1.w);
#pragma unroll
    for (int m = 1; m < 64; m <<= 1) { s += __shfl_xor(s, m); sq += __shfl_xor(sq, m); }
    float mu = s * (1.f / 512.f);
    float var = sq * (1.f / 512.f) - mu * mu;
    float rs = rsqrtf(var + 1e-5f);
    const float4* g4 = (const float4*)g;
    const float4* b4 = (const float4*)b;
    float4 gv = g4[lane], bv = b4[lane];
    ushort4 o;
    o.x = f2bf((v0.x - mu) * rs * gv.x + bv.x);
    o.y = f2bf((v0.y - mu) * rs * gv.y + bv.y);
    o.z = f2bf((v0.z - mu) * rs * gv.z + bv.z);
    o.w = f2bf((v0.w - mu) * rs * gv.w + bv.w);
    ((ushort4*)(out + row * 512))[lane] = o;
    gv = g4[lane + 64]; bv = b4[lane + 64];
    o.x = f2bf((v1.x - mu) * rs * gv.x + bv.x);
    o.y = f2bf((v1.y - mu) * rs * gv.y + bv.y);
    o.z = f2bf((v1.z - mu) * rs * gv.z + bv.z);
    o.w = f2bf((v1.w - mu) * rs * gv.w + bv.w);
    ((ushort4*)(out + row * 512))[lane + 64] = o;
}

// ---------------- 256x256 deep-pipelined GEMM ----------------
// C[M,N] = A[M,K](bf16) * Bt[N,K](bf16)^T + bias (+gelu / +resid)
// 512 threads = 8 waves (2M x 4N), wave tile 128x64, BK=64, double-buffered 128KB LDS.
// Staging: global_load_lds w=16, pre-swizzled source (chunk ^= row&7), swizzled ds_read.
// Pipeline: per K-tile, 4 quadrant phases; stage 1 panel (2 gld16) per phase into the
// other buffer; counted s_waitcnt vmcnt(2) ONCE per tile; raw s_barrier (2 per tile).
// EPI 0: bf16 out (bias); EPI 1: fp32 out (bias+resid); EPI 2: bf16 out (bias+gelu)
template <int EPI>
__global__ __launch_bounds__(512, 1) void gemm256(const U16* __restrict__ A,
                                                  const U16* __restrict__ Bt,
                                                  const float* __restrict__ bias,
                                                  const float* __restrict__ resid,
                                                  U16* __restrict__ outb,
                                                  float* __restrict__ outf,
                                                  int M, int N, int K, int gridN) {
    // buf c at c*32768 (U16): A tile [256][64] at +0, B tile [256][64] at +16384
    __shared__ __align__(16) U16 smem[65536];

    const int tid = threadIdx.x;
    const int lane = tid & 63, wv = tid >> 6;
    const int lo = lane & 15, hi = lane >> 4;
    const int wm = wv >> 2, wn = wv & 3;  // 2 x 4 wave grid

    const int nwg = gridDim.x, bid = blockIdx.x;
    const int swz = (bid & 7) * (nwg >> 3) + (bid >> 3);
    const int bn = swz % gridN, bm = swz / gridN;

    // staging source (pre-swizzled): thread -> row sr (+64 for line 1), phys chunk tid&7
    const int sr = tid >> 3;
    const int clog = (tid & 7) ^ (sr & 7);
    const U16* gA = A + (size_t)(bm * 256 + sr) * K + clog * 8;
    const U16* gB = Bt + (size_t)(bn * 256 + sr) * K + clog * 8;

// panel p of a matrix: rows [p*128, p*128+128); 2 gld16 per thread per panel
#define STAGE_PANEL(g, off, p)                                        \
    do {                                                              \
        U16* _l = smem + (off) + (p) * 8192 + tid * 8;                \
        gld16((g) + (size_t)((p) * 128) * K, _l);                     \
        gld16((g) + (size_t)((p) * 128 + 64) * K, _l + 4096);         \
    } while (0)

    // swizzled ds_read chunk offsets (U16 units) for kk=0,1
    const int ck0 = ((hi) ^ (lo & 7)) << 3;
    const int ck1 = ((4 | hi) ^ (lo & 7)) << 3;

    f32x4 acc[8][4] = {};

    // prologue: stage tile 0 into buf 0 (8 gld16/thread)
    STAGE_PANEL(gA, 0, 0);
    STAGE_PANEL(gB, 16384, 0);
    STAGE_PANEL(gA, 0, 1);
    STAGE_PANEL(gB, 16384, 1);
    gA += 64; gB += 64;

    const int nt = K >> 6;
    for (int t = 0; t < nt; ++t) {
        const int cb = (t & 1) << 15;
        const int nb = cb ^ 32768;
        const bool pf = (t < nt - 1);

        // ---- phase 1: stage A-panel0(next) ; publish tile t ; q00 ----
        if (pf) {
            STAGE_PANEL(gA, nb, 0);
            asm volatile("s_waitcnt vmcnt(2)" ::: "memory");
        } else {
            asm volatile("s_waitcnt vmcnt(0)" ::: "memory");
        }
        asm volatile("s_barrier" ::: "memory");

        const U16* Ab = smem + cb + (wm * 128 + lo) * 64;
        const U16* Bb = smem + cb + 16384 + (wn * 64 + lo) * 64;

        bf16x8 af[4][2], bg[4][2];
#pragma unroll
        for (int i = 0; i < 4; ++i) {
            af[i][0] = *(const bf16x8*)(Ab + i * 1024 + ck0);
            af[i][1] = *(const bf16x8*)(Ab + i * 1024 + ck1);
        }
#pragma unroll
        for (int j = 0; j < 2; ++j) {
            bg[j][0] = *(const bf16x8*)(Bb + j * 1024 + ck0);
            bg[j][1] = *(const bf16x8*)(Bb + j * 1024 + ck1);
        }
        __builtin_amdgcn_s_setprio(1);
#pragma unroll
        for (int i = 0; i < 4; ++i)
#pragma unroll
            for (int j = 0; j < 2; ++j) {
                acc[i][j] = MFMA_BF16(af[i][0], bg[j][0], acc[i][j], 0, 0, 0);
                acc[i][j] = MFMA_BF16(af[i][1], bg[j][1], acc[i][j], 0, 0, 0);
            }
        __builtin_amdgcn_s_setprio(0);

        // ---- phase 2: stage B-panel0(next) ; q01 (reuse A0-3, read B2-3) ----
        if (pf) STAGE_PANEL(gB, nb + 16384, 0);
#pragma unroll
        for (int j = 2; j < 4; ++j) {
            bg[j][0] = *(const bf16x8*)(Bb + j * 1024 + ck0);
            bg[j][1] = *(const bf16x8*)(Bb + j * 1024 + ck1);
        }
        __builtin_amdgcn_s_setprio(1);
#pragma unroll
        for (int i = 0; i < 4; ++i)
#pragma unroll
            for (int j = 2; j < 4; ++j) {
                acc[i][j] = MFMA_BF16(af[i][0], bg[j][0], acc[i][j], 0, 0, 0);
                acc[i][j] = MFMA_BF16(af[i][1], bg[j][1], acc[i][j], 0, 0, 0);
            }
        __builtin_amdgcn_s_setprio(0);

        // ---- phase 3: stage A-panel1(next) ; q10 (read A4-7, reuse B0-1) ----
        if (pf) STAGE_PANEL(gA, nb, 1);
#pragma unroll
        for (int i = 0; i < 4; ++i) {
            af[i][0] = *(const bf16x8*)(Ab + (i + 4) * 1024 + ck0);
            af[i][1] = *(const bf16x8*)(Ab + (i + 4) * 1024 + ck1);
        }
        __builtin_amdgcn_s_setprio(1);
#pragma unroll
        for (int i = 0; i < 4; ++i)
#pragma unroll
            for (int j = 0; j < 2; ++j) {
                acc[4 + i][j] = MFMA_BF16(af[i][0], bg[j][0], acc[4 + i][j], 0, 0, 0);
                acc[4 + i][j] = MFMA_BF16(af[i][1], bg[j][1], acc[4 + i][j], 0, 0, 0);
            }
        __builtin_amdgcn_s_setprio(0);

        // ---- phase 4: stage B-panel1(next) ; q11 (all regs resident) ----
        if (pf) STAGE_PANEL(gB, nb + 16384, 1);
        __builtin_amdgcn_s_setprio(1);
#pragma unroll
        for (int i = 0; i < 4; ++i)
#pragma unroll
            for (int j = 2; j < 4; ++j) {
                acc[4 + i][j] = MFMA_BF16(af[i][0], bg[j][0], acc[4 + i][j], 0, 0, 0);
                acc[4 + i][j] = MFMA_BF16(af[i][1], bg[j][1], acc[4 + i][j], 0, 0, 0);
            }
        __builtin_amdgcn_s_setprio(0);

        // end-of-tile: all waves done reading buf cb before next iter overwrites it
        asm volatile("s_barrier" ::: "memory");
        gA += 64; gB += 64;
    }

    // ---- epilogue: direct stores ----
    const int row0 = bm * 256 + wm * 128 + hi * 4;
    const int col0 = bn * 256 + wn * 64 + lo;
    float bc[4];
#pragma unroll
    for (int j = 0; j < 4; ++j) bc[j] = bias[col0 + j * 16];

    if (EPI == 1) {
#pragma unroll
        for (int i = 0; i < 8; ++i)
#pragma unroll
            for (int r = 0; r < 4; ++r) {
                const size_t rowb = (size_t)(row0 + i * 16 + r) * N;
#pragma unroll
                for (int j = 0; j < 4; ++j) {
                    const size_t idx = rowb + col0 + j * 16;
                    outf[idx] = acc[i][j][r] + bc[j] + resid[idx];
                }
            }
    } else {
#pragma unroll
        for (int i = 0; i < 8; ++i)
#pragma unroll
            for (int j = 0; j < 4; ++j)
#pragma unroll
                for (int r = 0; r < 4; ++r) {
                    float v = acc[i][j][r] + bc[j];
                    if (EPI == 2) v = 0.5f * v * (1.f + erff(v * 0.70710678118654752f));
                    outb[(size_t)(row0 + i * 16 + r) * N + col0 + j * 16] = f2bf(v);
                }
    }
#undef STAGE_PANEL
}

// ---------------- windowed attention: one block per (window, head) ----------------
// qkv: [32768][1536] bf16, layout [3][8][64] in last dim. o: [32768][512] bf16.
__global__ __launch_bounds__(256) void attn_kernel(const U16* __restrict__ qkv,
                                                   U16* __restrict__ o) {
    const int blk = blockIdx.x;
    const int w = blk >> 3, h = blk & 7;
    const int tid = threadIdx.x;
    const int lane = tid & 63, wv = tid >> 6;
    const int lo = lane & 15, hi = lane >> 4;

    __shared__ __align__(16) U16 Qs[64][72];
    __shared__ __align__(16) U16 Ks[64][72];
    __shared__ __align__(16) U16 Vt[64][72];  // V transposed: Vt[d][j]
    __shared__ __align__(16) U16 Ps[4][16][72];

    {
        const int r = tid >> 2;
        const int c0 = (tid & 3) << 4;
        const U16* p = qkv + (size_t)(w * 64 + r) * 1536 + h * 64 + c0;
        *(bf16x8*)&Ks[r][c0] = *(const bf16x8*)(p + 512);
        *(bf16x8*)&Ks[r][c0 + 8] = *(const bf16x8*)(p + 520);
        const U16* pv = p + 1024;
#pragma unroll
        for (int i = 0; i < 16; i++) Vt[c0 + i][r] = pv[i];
#pragma unroll
        for (int i = 0; i < 16; i++) Qs[r][c0 + i] = f2bf(bf2f(p[i]) * 0.125f);
    }
    __syncthreads();

    const int rb = wv * 16;  // this wave's 16 score rows
    f32x4 s[4] = {};
#pragma unroll
    for (int dc = 0; dc < 64; dc += 32) {
        bf16x8 a = *(const bf16x8*)&Qs[rb + lo][dc + hi * 8];
#pragma unroll
        for (int jb = 0; jb < 4; jb++) {
            bf16x8 bfr = *(const bf16x8*)&Ks[jb * 16 + lo][dc + hi * 8];
            s[jb] = MFMA_BF16(a, bfr, s[jb], 0, 0, 0);
        }
    }
#pragma unroll
    for (int r = 0; r < 4; r++) {
        float m = fmaxf(fmaxf(s[0][r], s[1][r]), fmaxf(s[2][r], s[3][r]));
#pragma unroll
        for (int msk = 1; msk < 16; msk <<= 1) m = fmaxf(m, __shfl_xor(m, msk));
        float e[4], sum = 0.f;
#pragma unroll
        for (int jb = 0; jb < 4; jb++) { e[jb] = expf(s[jb][r] - m); sum += e[jb]; }
#pragma unroll
        for (int msk = 1; msk < 16; msk <<= 1) sum += __shfl_xor(sum, msk);
        float inv = 1.f / sum;
#pragma unroll
        for (int jb = 0; jb < 4; jb++) Ps[wv][hi * 4 + r][jb * 16 + lo] = f2bf(e[jb] * inv);
    }
    __syncthreads();

    f32x4 oa[4] = {};
#pragma unroll
    for (int jc = 0; jc < 64; jc += 32) {
        bf16x8 a = *(const bf16x8*)&Ps[wv][lo][jc + hi * 8];
#pragma unroll
        for (int db = 0; db < 4; db++) {
            bf16x8 bfr = *(const bf16x8*)&Vt[db * 16 + lo][jc + hi * 8];
            oa[db] = MFMA_BF16(a, bfr, oa[db], 0, 0, 0);
        }
    }
#pragma unroll
    for (int db = 0; db < 4; db++)
#pragma unroll
        for (int r = 0; r < 4; r++)
            o[(size_t)(w * 64 + rb + hi * 4 + r) * 512 + h * 64 + db * 16 + lo] = f2bf(oa[db][r]);
}

// ---------------- launch ----------------
extern "C" void kernel_launch(void* const* d_in, const int* in_sizes, int n_in,
                              void* d_out, int out_size, void* d_ws, size_t ws_size,
                              hipStream_t stream) {
    const float* x = (const float*)d_in[0];
    const float* ln1_g = (const float*)d_in[1];
    const float* ln1_b = (const float*)d_in[2];
    const float* qkv_w = (const float*)d_in[3];
    const float* qkv_b = (const float*)d_in[4];
    const float* proj_w = (const float*)d_in[5];
    const float* proj_b = (const float*)d_in[6];
    const float* ln2_g = (const float*)d_in[7];
    const float* ln2_b = (const float*)d_in[8];
    const float* fc1_w = (const float*)d_in[9];
    const float* fc1_b = (const float*)d_in[10];
    const float* fc2_w = (const float*)d_in[11];
    const float* fc2_b = (const float*)d_in[12];
    float* out = (float*)d_out;

    char* ws = (char*)d_ws;
    U16* hbuf = (U16*)ws;                               // 32768*512 bf16
    U16* big = (U16*)(ws + 33554432);                   // 32768*2048 bf16 max
    U16* wt_qkv = (U16*)(ws + 33554432 + 134217728);    // 1536*512
    U16* wt_proj = wt_qkv + 1536 * 512;                 // 512*512
    U16* wt_fc1 = wt_proj + 512 * 512;                  // 2048*512
    U16* wt_fc2 = wt_fc1 + 2048 * 512;                  // 512*2048

    dim3 tb(32, 8);
    tcast_kernel<<<dim3(1536 / 32, 512 / 32), tb, 0, stream>>>(qkv_w, wt_qkv, 512, 1536);
    tcast_kernel<<<dim3(512 / 32, 512 / 32), tb, 0, stream>>>(proj_w, wt_proj, 512, 512);
    tcast_kernel<<<dim3(2048 / 32, 512 / 32), tb, 0, stream>>>(fc1_w, wt_fc1, 512, 2048);
    tcast_kernel<<<dim3(512 / 32, 2048 / 32), tb, 0, stream>>>(fc2_w, wt_fc2, 2048, 512);

    ln_kernel<<<8192, 256, 0, stream>>>(x, ln1_g, ln1_b, hbuf);
    gemm256<0><<<768, 512, 0, stream>>>(hbuf, wt_qkv, qkv_b, nullptr, big, nullptr, 32768, 1536, 512, 6);
    attn_kernel<<<4096, 256, 0, stream>>>(big, hbuf);
    gemm256<1><<<256, 512, 0, stream>>>(hbuf, wt_proj, proj_b, x, nullptr, out, 32768, 512, 512, 2);
    ln_kernel<<<8192, 256, 0, stream>>>(out, ln2_g, ln2_b, hbuf);
    gemm256<2><<<1024, 512, 0, stream>>>(hbuf, wt_fc1, fc1_b, nullptr, big, nullptr, 32768, 2048, 512, 8);
    gemm256<1><<<256, 512, 0, stream>>>(big, wt_fc2, fc2_b, out, nullptr, out, 32768, 512, 2048, 2);
}